// Round 7
// baseline (20.752 us; speedup 1.0000x reference)
//
#include <hip/hip_runtime.h>

#define EMBED  128
#define BATCH  64
#define SEQLEN 2048
#define NSLICE 8                 // slices of the 128-float row
#define SLICEF 16                // floats per slice (64 B)
#define BLOCK  512
#define NROWG  (BLOCK / 4)       // 128 row-groups (4 lanes x float4 = one slice)
#define TOKPG  (SEQLEN / NROWG)  // 16 tokens per row-group

__device__ __forceinline__ float4 f4add(const float4 a, const float4 b) {
    return make_float4(a.x + b.x, a.y + b.y, a.z + b.z, a.w + b.w);
}
__device__ __forceinline__ float4 f4sub(const float4 a, const float4 b) {
    return make_float4(a.x - b.x, a.y - b.y, a.z - b.z, a.w - b.w);
}
__device__ __forceinline__ float4 f4shfl_xor(const float4 v, int mask) {
    return make_float4(__shfl_xor(v.x, mask), __shfl_xor(v.y, mask),
                       __shfl_xor(v.z, mask), __shfl_xor(v.w, mask));
}

// ---------------------------------------------------------------------------
// One-pass CBOW, 8 x 64B slices -> 512 blocks (2 blocks/CU, 4 waves/SIMD).
// idx = b<<3 | sl, so blockIdx%8 == sl: slice sl's 6.4 MB column is read
// only by the 64 blocks on XCD sl (L2 affinity).
//   c = tid & 3  -> float4 within the slice (4 lanes * 16 B = 64 B segment)
//   r = tid >> 2 -> row-group 0..127, owns tokens r, r+128, ... (16 each)
// Tokens loaded straight from global (uniform per 4-lane group, broadcast).
// Reduce: 4 shfl_xor rounds in-wave (16 row-groups/wave) -> psum[8][4] ->
// 1 barrier -> wave-0 butterfly -> 16-lane epilogue with hoisted corrections.
// ---------------------------------------------------------------------------
__global__ __launch_bounds__(BLOCK) void cbow_onepass_kernel(
    const int* __restrict__ x, const float* __restrict__ emb,
    float* __restrict__ out) {
    const int idx = blockIdx.x;
    const int sl  = idx & 7;
    const int b   = idx >> 3;
    const int tid = threadIdx.x;
    const int c   = tid & 3;
    const int r   = tid >> 2;   // row-group 0..127
    const int w   = tid >> 6;   // wave 0..7
    const int ln  = tid & 63;   // lane

    const int*   xb   = x + b * SEQLEN;
    const float* embs = emb + sl * SLICEF + c * 4;

    // --- Hoisted epilogue loads (lanes 0..15): issue early, use at the end.
    float4 e0v, v0v, v1v, vl2v, vl1v;
    if (tid < 16) {
        const int t0  = xb[0];
        const int t1  = xb[1];
        const int tl2 = xb[SEQLEN - 2];
        const int tl1 = xb[SEQLEN - 1];
        e0v  = *reinterpret_cast<const float4*>(embs);
        v0v  = *reinterpret_cast<const float4*>(embs + (size_t)t0  * EMBED);
        v1v  = *reinterpret_cast<const float4*>(embs + (size_t)t1  * EMBED);
        vl2v = *reinterpret_cast<const float4*>(embs + (size_t)tl2 * EMBED);
        vl1v = *reinterpret_cast<const float4*>(embs + (size_t)tl1 * EMBED);
    }

    // --- Token loads: 16 independent uniform loads per row-group.
    int tk[TOKPG];
#pragma unroll
    for (int it = 0; it < TOKPG; ++it) tk[it] = xb[r + NROWG * it];

    // --- Gather + accumulate: 4 independent accumulators, fully unrolled.
    float4 acc[4];
#pragma unroll
    for (int i = 0; i < 4; ++i) acc[i] = make_float4(0.f, 0.f, 0.f, 0.f);
#pragma unroll
    for (int it = 0; it < TOKPG; ++it) {
        const float4 v = *reinterpret_cast<const float4*>(
            embs + (size_t)tk[it] * EMBED);
        acc[it & 3] = f4add(acc[it & 3], v);
    }
    float4 a = f4add(f4add(acc[0], acc[1]), f4add(acc[2], acc[3]));

    // --- In-wave reduce across the 16 row-groups (lane bits 2..5).
    a = f4add(a, f4shfl_xor(a, 4));
    a = f4add(a, f4shfl_xor(a, 8));
    a = f4add(a, f4shfl_xor(a, 16));
    a = f4add(a, f4shfl_xor(a, 32));

    __shared__ float4 psum[8][4];
    if (ln < 4) psum[w][c] = a;   // lane ln == c here
    __syncthreads();

    // --- Wave 0: butterfly over the 8 per-wave partials (lane bits 2..4);
    //     lanes 0..31 end holding the total for column c = ln & 3.
    if (w == 0) {
        const int g = ln >> 2;  // 0..15 (psum index mod 8)
        float4 t = psum[g & 7][c];
        t = f4add(t, f4shfl_xor(t, 4));
        t = f4add(t, f4shfl_xor(t, 8));
        t = f4add(t, f4shfl_xor(t, 16));

        // --- Epilogue: lanes 0..15, o = output row 0..3.
        if (ln < 16) {
            const int o = ln >> 2;
            float4 res = f4add(t, e0v);
            if (o == 0) {
                res = f4sub(res, vl1v);                            // offset -1
            } else if (o == 1) {
                res = f4add(f4sub(f4sub(res, vl1v), vl2v), e0v);   // offset -2
            } else if (o == 2) {
                res = f4sub(res, v0v);                             // offset +1
            } else {
                res = f4add(f4sub(f4sub(res, v0v), v1v), e0v);     // offset +2
            }
            *reinterpret_cast<float4*>(
                out + ((size_t)b * 4 + o) * EMBED + sl * SLICEF + c * 4) = res;
        }
    }
}

extern "C" void kernel_launch(void* const* d_in, const int* in_sizes, int n_in,
                              void* d_out, int out_size, void* d_ws, size_t ws_size,
                              hipStream_t stream) {
    const int*   x   = (const int*)d_in[0];
    const float* emb = (const float*)d_in[1];
    float*       out = (float*)d_out;

    cbow_onepass_kernel<<<dim3(BATCH * NSLICE), dim3(BLOCK), 0, stream>>>(
        x, emb, out);
}

// Round 8
// 16.076 us; speedup vs baseline: 1.2908x; 1.2908x over previous
//
#include <hip/hip_runtime.h>

#define EMBED  128
#define BATCH  64
#define SEQLEN 2048
#define NSLICE 4                 // slices of the 128-float row (128 B each = 1 line)
#define SLICEF 32                // floats per slice
#define BLOCK  512
#define NROWG  (BLOCK / 8)       // 64 row-groups (8 lanes x float4 = one slice)
#define TOKPG  (SEQLEN / NROWG)  // 32 tokens per row-group

__device__ __forceinline__ float4 f4add(const float4 a, const float4 b) {
    return make_float4(a.x + b.x, a.y + b.y, a.z + b.z, a.w + b.w);
}
__device__ __forceinline__ float4 f4sub(const float4 a, const float4 b) {
    return make_float4(a.x - b.x, a.y - b.y, a.z - b.z, a.w - b.w);
}
__device__ __forceinline__ float4 f4shfl_xor(const float4 v, int mask) {
    return make_float4(__shfl_xor(v.x, mask), __shfl_xor(v.y, mask),
                       __shfl_xor(v.z, mask), __shfl_xor(v.w, mask));
}

// ---------------------------------------------------------------------------
// One-pass CBOW (best-measured config, = R6).
// 128 B slices: one block owns one cacheline-column of the table -> no
// cross-XCD line sharing (R7 showed 64 B slices double L3 traffic: 14->21us).
// grid.x = 256; idx = (b>>1)<<3 | sl<<1 | (b&1): slice sl -> XCDs {2sl,2sl+1}.
//   c = tid & 7  -> float4 within the slice (8 lanes * 16 B = 128 B segment)
//   r = tid >> 3 -> row-group 0..63, owns tokens r, r+64, ... (32 each)
// Tokens loaded straight from global (uniform per 8-lane group, broadcast);
// no LDS staging barrier. 8 independent accumulators.
// Reduce: 3 shfl_xor rounds in-wave -> psum[8][8] -> 1 barrier -> wave-0
// butterfly -> 32-lane epilogue with hoisted boundary corrections.
// ---------------------------------------------------------------------------
__global__ __launch_bounds__(BLOCK) void cbow_onepass_kernel(
    const int* __restrict__ x, const float* __restrict__ emb,
    float* __restrict__ out) {
    const int idx = blockIdx.x;
    const int sl  = (idx & 7) >> 1;
    const int b   = ((idx >> 3) << 1) | (idx & 1);
    const int tid = threadIdx.x;
    const int c   = tid & 7;
    const int r   = tid >> 3;   // row-group 0..63
    const int w   = tid >> 6;   // wave 0..7
    const int ln  = tid & 63;   // lane

    const int*   xb   = x + b * SEQLEN;
    const float* embs = emb + sl * SLICEF + c * 4;

    // --- Hoisted epilogue loads (lanes 0..31): issue early, use at the end.
    float4 e0v, v0v, v1v, vl2v, vl1v;
    if (tid < 32) {
        const int t0  = xb[0];
        const int t1  = xb[1];
        const int tl2 = xb[SEQLEN - 2];
        const int tl1 = xb[SEQLEN - 1];
        e0v  = *reinterpret_cast<const float4*>(embs);
        v0v  = *reinterpret_cast<const float4*>(embs + (size_t)t0  * EMBED);
        v1v  = *reinterpret_cast<const float4*>(embs + (size_t)t1  * EMBED);
        vl2v = *reinterpret_cast<const float4*>(embs + (size_t)tl2 * EMBED);
        vl1v = *reinterpret_cast<const float4*>(embs + (size_t)tl1 * EMBED);
    }

    // --- Token loads: 32 independent uniform loads per row-group.
    int tk[TOKPG];
#pragma unroll
    for (int it = 0; it < TOKPG; ++it) tk[it] = xb[r + NROWG * it];

    // --- Gather + accumulate: 8 independent accumulators, fully unrolled.
    float4 acc[8];
#pragma unroll
    for (int i = 0; i < 8; ++i) acc[i] = make_float4(0.f, 0.f, 0.f, 0.f);
#pragma unroll
    for (int it = 0; it < TOKPG; ++it) {
        const float4 v = *reinterpret_cast<const float4*>(
            embs + (size_t)tk[it] * EMBED);
        acc[it & 7] = f4add(acc[it & 7], v);
    }
    float4 s01 = f4add(acc[0], acc[1]);
    float4 s23 = f4add(acc[2], acc[3]);
    float4 s45 = f4add(acc[4], acc[5]);
    float4 s67 = f4add(acc[6], acc[7]);
    float4 a = f4add(f4add(s01, s23), f4add(s45, s67));

    // --- In-wave reduce across the 8 row-groups (lane bits 3..5).
    a = f4add(a, f4shfl_xor(a, 8));
    a = f4add(a, f4shfl_xor(a, 16));
    a = f4add(a, f4shfl_xor(a, 32));

    __shared__ float4 psum[8][8];
    if (ln < 8) psum[w][c] = a;   // lane ln == c here
    __syncthreads();

    // --- Wave 0: butterfly over the 8 per-wave partials; lanes 0..31 end
    //     holding the total for their column c.
    if (w == 0) {
        const int g = ln >> 3;  // 0..7
        float4 t = psum[g & 7][c];
        t = f4add(t, f4shfl_xor(t, 8));
        t = f4add(t, f4shfl_xor(t, 16));
        t = f4add(t, f4shfl_xor(t, 32));

        // --- Epilogue: lanes 0..31, o = output row 0..3.
        if (ln < 32) {
            const int o = ln >> 3;
            float4 res = f4add(t, e0v);
            if (o == 0) {
                res = f4sub(res, vl1v);                            // offset -1
            } else if (o == 1) {
                res = f4add(f4sub(f4sub(res, vl1v), vl2v), e0v);   // offset -2
            } else if (o == 2) {
                res = f4sub(res, v0v);                             // offset +1
            } else {
                res = f4add(f4sub(f4sub(res, v0v), v1v), e0v);     // offset +2
            }
            *reinterpret_cast<float4*>(
                out + ((size_t)b * 4 + o) * EMBED + sl * SLICEF + c * 4) = res;
        }
    }
}

extern "C" void kernel_launch(void* const* d_in, const int* in_sizes, int n_in,
                              void* d_out, int out_size, void* d_ws, size_t ws_size,
                              hipStream_t stream) {
    const int*   x   = (const int*)d_in[0];
    const float* emb = (const float*)d_in[1];
    float*       out = (float*)d_out;

    cbow_onepass_kernel<<<dim3(BATCH * NSLICE), dim3(BLOCK), 0, stream>>>(
        x, emb, out);
}